// Round 13
// baseline (4867.849 us; speedup 1.0000x reference)
//
#include <hip/hip_runtime.h>
#include <hip/hip_cooperative_groups.h>

namespace cg = cooperative_groups;

#define Bb 64
#define Ss 128
#define Tt 128
#define Ee 512
#define Hh 1024
#define GRID 256
#define NTHR 512
#define GSTRIDE (GRID * NTHR)

using short8 = __attribute__((ext_vector_type(8))) short;
using f32x4  = __attribute__((ext_vector_type(4))) float;
typedef unsigned long long u64;

// ---- ws layout (byte offsets), total ~55.1 MiB ----
#define PK_OFF    0u            // ushort [8192][1024]  proj_key bf16 (dead after pin)
#define EPART_OFF PK_OFF        // float [64 b][4 hq][128 s]  (overlays pk, 128 KB)
#define ENC_OFF   16777216u     // ushort [64][128][1024] enc bf16
#define WQF_OFF   33554432u     // frag [64 nt][32 kt][64][8]   (contiguous with WHHF:
#define WHHF_OFF  35651584u     // frag [192 nt][32 kt][64][8]   unified nt = 0..255)
#define WIHF_OFF  41943040u     // frag [192 nt][48 kt][64][8] (perm rows)
#define WKF_OFF   51380224u     // frag [64 nt][32 kt][64][8]
#define QWS_OFF   53477376u     // float [64][1024]
#define GHWS_OFF  53739520u     // float [192 ntp][64 b][16 jj]
#define CTXF_OFF  54525952u     // frag A [4 btile][32 kt][64][8]  (128 KB)
#define HFRG_OFF  54657024u     // frag A [4 btile][32 kt][64][8]  (128 KB)
#define HPRV_OFF  54788096u     // float [64][1024]
#define FLG_OFF   55050240u     // uint region: dataflow flags/counters (64 KB)

__device__ __forceinline__ float fast_tanh(float x) {
  float e = __expf(2.0f * x);
  return 1.0f - __fdividef(2.0f, e + 1.0f);
}
__device__ __forceinline__ float fast_sig(float x) {
  return __fdividef(1.0f, 1.0f + __expf(-x));
}
__device__ __forceinline__ unsigned f2bf(float x) {
  union { float f; unsigned u; } v; v.f = x;
  unsigned r = v.u + 0x7fffu + ((v.u >> 16) & 1u);
  return (r >> 16);
}
__device__ __forceinline__ uint4 pack8(float4 a, float4 b) {
  uint4 u;
  u.x = f2bf(a.x) | (f2bf(a.y) << 16);
  u.y = f2bf(a.z) | (f2bf(a.w) << 16);
  u.z = f2bf(b.x) | (f2bf(b.y) << 16);
  u.w = f2bf(b.z) | (f2bf(b.w) << 16);
  return u;
}
__device__ __forceinline__ void cvt8_store(const float* src, unsigned short* dst) {
  float4 f0 = *(const float4*)src, f1 = *(const float4*)(src + 4);
  *(uint4*)dst = pack8(f0, f1);
}
__device__ __forceinline__ short8 ld_frag(const unsigned short* base, int tile, int lane) {
  return *(const short8*)(base + ((size_t)tile * 64 + lane) * 8);
}
__device__ __forceinline__ short8 cvt8_reg(const float* src) {
  float4 f0 = *(const float4*)src, f1 = *(const float4*)(src + 4);
  union { uint4 u; short8 s; } cv; cv.u = pack8(f0, f1);
  return cv.s;
}

// ---- coherent (device-scope, L2-safe) access helpers ----
__device__ __forceinline__ u64 ld_coh8(const void* p) {
  return __hip_atomic_load((const u64*)p, __ATOMIC_RELAXED, __HIP_MEMORY_SCOPE_AGENT);
}
__device__ __forceinline__ void st_coh8(void* p, u64 v) {
  __hip_atomic_store((u64*)p, v, __ATOMIC_RELAXED, __HIP_MEMORY_SCOPE_AGENT);
}
__device__ __forceinline__ unsigned ld_coh1(const void* p) {
  return __hip_atomic_load((const unsigned*)p, __ATOMIC_RELAXED, __HIP_MEMORY_SCOPE_AGENT);
}
__device__ __forceinline__ void st_coh1(void* p, unsigned v) {
  __hip_atomic_store((unsigned*)p, v, __ATOMIC_RELAXED, __HIP_MEMORY_SCOPE_AGENT);
}
__device__ __forceinline__ void add_coh1(void* p, unsigned v) {
  __hip_atomic_fetch_add((unsigned*)p, v, __ATOMIC_RELAXED, __HIP_MEMORY_SCOPE_AGENT);
}
__device__ __forceinline__ u64 f2u64(float a, float b) {
  union { float f[2]; u64 u; } c; c.f[0] = a; c.f[1] = b; return c.u;
}
__device__ __forceinline__ float u64lo(u64 v) {
  union { unsigned u; float f; } c; c.u = (unsigned)v; return c.f;
}
__device__ __forceinline__ float u64hi(u64 v) {
  union { unsigned u; float f; } c; c.u = (unsigned)(v >> 32); return c.f;
}

// producer arrive: drain stores block-wide, then tid0 sets/bumps the flag
#define ARRIVE_PRE() do { \
  asm volatile("s_waitcnt vmcnt(0)" ::: "memory"); \
  __syncthreads(); } while (0)

template <int K, bool PERM>
__device__ void conv_frag(const float* __restrict__ W, unsigned short* __restrict__ F,
                          int gtid, int total) {
  const int kpg = K / 8;
  for (int i = gtid; i < total; i += GSTRIDE) {
    int np = i / kpg, kg = i - np * kpg;
    int row;
    if (PERM) {
      int ntp = np >> 4, jb = ntp / 3, g = ntp - jb * 3;
      row = g * 1024 + jb * 16 + (np & 15);
    } else row = np;
    int k0 = kg * 8;
    int kt = k0 >> 5, quad = (k0 >> 3) & 3;
    int lane_f = (np & 15) | (quad << 4);
    size_t dst = ((size_t)((np >> 4) * (K / 32) + kt) * 64 + lane_f) * 8;
    cvt8_store(W + (size_t)row * K + k0, F + dst);
  }
}

__global__ void __launch_bounds__(NTHR, 2)
bahdanau_kernel(const float* __restrict__ inputs,
                const float* __restrict__ enc,
                const float* __restrict__ finals,
                const float* __restrict__ Wk,
                const float* __restrict__ Wq,
                const float* __restrict__ vatt,
                const float* __restrict__ Wih,
                const float* __restrict__ Whh,
                const float* __restrict__ bih,
                const float* __restrict__ bhh,
                float* __restrict__ dout,
                char* __restrict__ wsb)
{
  cg::grid_group grid = cg::this_grid();
  __shared__ unsigned short pk_l[128][256];
  __shared__ char scr[40960];

  const int tid  = threadIdx.x;
  const int bid  = blockIdx.x;
  const int lane = tid & 63;
  const int wv   = __builtin_amdgcn_readfirstlane(tid >> 6);   // 0..7
  const int gtid = bid * NTHR + tid;
  const int quad = lane >> 4, col = lane & 15;

  unsigned short* pk   = (unsigned short*)(wsb + PK_OFF);
  float*          epart= (float*)(wsb + EPART_OFF);
  unsigned short* encb = (unsigned short*)(wsb + ENC_OFF);
  unsigned short* wqf  = (unsigned short*)(wsb + WQF_OFF);  // unified nt 0..255 (wq|whh)
  unsigned short* wihf = (unsigned short*)(wsb + WIHF_OFF);
  unsigned short* wkf  = (unsigned short*)(wsb + WKF_OFF);
  float* qws  = (float*)(wsb + QWS_OFF);
  float* ghws = (float*)(wsb + GHWS_OFF);
  unsigned short* ctxf = (unsigned short*)(wsb + CTXF_OFF);
  unsigned short* hfrg = (unsigned short*)(wsb + HFRG_OFF);
  float* hprv = (float*)(wsb + HPRV_OFF);
  unsigned* flags = (unsigned*)(wsb + FLG_OFF);
  // dataflow state, all slots 128B-strided, monotone (never reset):
  unsigned* af = flags;              // [256 blk]  A done (q/gh stored), value t+1
  unsigned* mb = flags + 8192;       // [64 batt]  B1 arrivals (4/step)
  unsigned* cc = flags + 10240;      // [64 batt]  B2 ctx-stored arrivals (4/step)
  unsigned* hc = flags + 12288;      // [4 bt][8]  C done arrivals (8/step each)
  // rc REMOVED (r12): proven redundant — hc(t-1) >= 8t is implied transitively
  // via B1's af-wait (af >= t+1 requires A to pass hc-wait, which counts full
  // C(t-1) completion incl. ctx staging). ha retained (gh-window A-blocks are
  // NOT covered by that chain).
  unsigned* ha = flags + 14336;      // [4 bt][8]  A staged hfrg (reader release, 8/step)
  float* hidout = dout;
  float* outs   = dout + Bb * Hh;

  const int batt = bid & 63;          // attention batch
  const int hq   = bid >> 6;          // H quarter

  // ================= P0: conversions + flag init ====
  for (int i = gtid; i < 16384; i += GSTRIDE) flags[i] = 0u;
  for (int i = gtid; i < 1048576; i += GSTRIDE)
    cvt8_store(enc + (size_t)i * 8, encb + (size_t)i * 8);
  conv_frag<1024, false>(Wq,  wqf,  gtid, 131072);
  conv_frag<1024, false>(Wk,  wkf,  gtid, 131072);
  conv_frag<1024, true >(Whh, (unsigned short*)(wsb + WHHF_OFF), gtid, 393216);
  conv_frag<1536, true >(Wih, wihf, gtid, 589824);
  for (int i = gtid; i < 8192; i += GSTRIDE) {
    int b = i >> 7, kg = i & 127, k0 = kg * 8;
    int kt = k0 >> 5, qd = (k0 >> 3) & 3;
    int lf = (b & 15) | (qd << 4);
    cvt8_store(finals + (size_t)b * Hh + k0,
               hfrg + ((size_t)((b >> 4) * 32 + kt) * 64 + lf) * 8);
  }
  for (int i = gtid; i < 16384; i += GSTRIDE)
    ((float4*)hprv)[i] = ((const float4*)finals)[i];
  grid.sync();

  // ---- Phase-A tiling (r9): window wA (4 col-tiles) x batch-tile btA ----
  const int wA  = (bid & 7) * 8 + (bid >> 5);    // 0..63
  const int btA = (bid >> 3) & 3;                // 0..3
  const int cgA = wv & 3;
  const int khA = wv >> 2;
  const int ntA = wA * 4 + cgA;                  // unified col-tile 0..255
  short8 wAB[16];
  #pragma unroll
  for (int i = 0; i < 16; ++i)
    wAB[i] = ld_frag(wqf, ntA * 32 + khA * 16 + i, lane);

  // Phase-C role (r9 remap)
  const int cxC = bid & 7, cmC = bid >> 3;
  const int jbC = cxC * 8 + (cmC >> 2);   // 0..63
  const int bqC = cmC & 3;                // 0..3

  // ---- dataflow producer ids (precomputed) ----
  // B1 q-producers: windows hq*4+g, batch-tile batt>>4
  int pqsel;
  {
    int g = lane & 3;
    int wq = hq * 4 + g;
    pqsel = (wq & 7) * 32 + (batt >> 4) * 8 + (wq >> 3);
  }
  // C gh-producers: windows covering col-tiles 64+3*jbC .. 66+3*jbC, bt=bqC
  int pghsel2;
  {
    int wg0 = (64 + 3 * jbC) >> 2, wg1 = (66 + 3 * jbC) >> 2;
    int wgx = (lane & 1) ? wg1 : wg0;
    pghsel2 = (wgx & 7) * 32 + bqC * 8 + (wgx >> 3);
  }

  // vatt slice for B1 — hoisted
  float vr2[4];
  {
    float4 vv = *(const float4*)(vatt + hq * 256 + lane * 4);
    vr2[0] = vv.x; vr2[1] = vv.y; vr2[2] = vv.z; vr2[3] = vv.w;
  }

  // Phase-C loop-invariant gate biases (hoisted out of t-loop)
  const int blocC = tid >> 3, jpC = tid & 7;
  const int bC    = bqC * 16 + blocC;
  const int j0pC  = jbC * 16 + jpC * 2;
  float2 bi0v = {0,0}, bi1v = {0,0}, bi2v = {0,0};
  float2 bh0v = {0,0}, bh1v = {0,0}, bh2v = {0,0};
  if (tid < 128) {
    bi0v = *(const float2*)&bih[0 * 1024 + j0pC];
    bi1v = *(const float2*)&bih[1 * 1024 + j0pC];
    bi2v = *(const float2*)&bih[2 * 1024 + j0pC];
    bh0v = *(const float2*)&bhh[0 * 1024 + j0pC];
    bh1v = *(const float2*)&bhh[1 * 1024 + j0pC];
    bh2v = *(const float2*)&bhh[2 * 1024 + j0pC];
  }

  // ================= P0b: proj_key = enc @ Wk^T (MFMA) =================
  {
    const int W = bid * 8 + wv;
    const int mt = W >> 2;
    const int ng = W & 3;
    for (int nt2 = 0; nt2 < 16; ++nt2) {
      int nt = ng * 16 + nt2;
      f32x4 acc = {0.f, 0.f, 0.f, 0.f};
      for (int kt = 0; kt < 32; ++kt) {
        short8 a = *(const short8*)(encb + (size_t)(mt * 16 + col) * Hh + kt * 32 + quad * 8);
        short8 b = ld_frag(wkf, nt * 32 + kt, lane);
        acc = __builtin_amdgcn_mfma_f32_16x16x32_bf16(a, b, acc, 0, 0, 0);
      }
      #pragma unroll
      for (int r = 0; r < 4; ++r)
        pk[(size_t)(mt * 16 + quad * 4 + r) * Hh + nt * 16 + col] = (unsigned short)f2bf(acc[r]);
    }
  }
  grid.sync();

  // ---- pin pk slice [128 s][256 h] into LDS ----
  {
    const unsigned short* src = pk + (size_t)batt * Ss * Hh + hq * 256;
    int s = tid >> 2, pq = tid & 3;
    #pragma unroll
    for (int i = 0; i < 8; ++i)
      *(uint4*)&pk_l[s][pq * 64 + i * 8] =
        *(const uint4*)(src + (size_t)s * Hh + pq * 64 + i * 8);
  }
  __syncthreads();

  for (int t = 0; t < Tt; ++t) {
    const unsigned genA = (unsigned)(t + 1);

    // ===== A-wait: hfrg tile btA fully rewritten by C(t-1) =====
    __syncthreads();
    if (t > 0 && tid < 64) {
      unsigned tgt = 8u * (unsigned)t;
      for (;;) {
        bool ok = true;
        if (lane < 8) ok = ld_coh1(&hc[(btA * 8 + lane) * 32]) >= tgt;
        if (__all(ok)) break;
        __builtin_amdgcn_s_sleep(1);
      }
    }
    __syncthreads();

    // ===== Phase A: [q ; gh] tile (16 b x 64 cols), h-slice staged in LDS =====
    {
      {
        u64* l8 = (u64*)scr;
        const u64* g8 = (const u64*)(hfrg + (size_t)btA * 32 * 64 * 8);
        u64 r[8];
        #pragma unroll
        for (int i = 0; i < 8; ++i) r[i] = ld_coh8(g8 + tid + i * NTHR);
        #pragma unroll
        for (int i = 0; i < 8; ++i) l8[tid + i * NTHR] = r[i];
      }
      __syncthreads();
      if (tid == 0) add_coh1(&ha[(btA * 8 + (wA >> 3)) * 32], 1u);  // release hfrg readers
      const unsigned short* hl = (const unsigned short*)scr;
      f32x4 acc = {0.f, 0.f, 0.f, 0.f};
      #pragma unroll
      for (int i = 0; i < 16; ++i) {
        int kt = khA * 16 + i;
        short8 a = *(const short8*)(hl + ((size_t)kt * 64 + lane) * 8);
        acc = __builtin_amdgcn_mfma_f32_16x16x32_bf16(a, wAB[i], acc, 0, 0, 0);
      }
      __syncthreads();
      float* part = (float*)(scr + 32768);   // [4 r][8 wv][64 lane]
      #pragma unroll
      for (int r = 0; r < 4; ++r) part[r * 512 + wv * 64 + lane] = acc[r];
      __syncthreads();
      {
        int cg = tid >> 7, rem = tid & 127;
        int qd = rem >> 5, r = (rem >> 3) & 3, clp = rem & 7;
        float v2[2];
        #pragma unroll
        for (int jj = 0; jj < 2; ++jj) {
          int cl = clp * 2 + jj;
          int ln = (qd << 4) | cl;
          v2[jj] = part[r * 512 + cg * 64 + ln]
                 + part[r * 512 + (4 + cg) * 64 + ln];
        }
        int b = btA * 16 + qd * 4 + r;
        int nt_g = wA * 4 + cg;
        if (nt_g < 64)
          st_coh8(&qws[(size_t)b * Hh + nt_g * 16 + clp * 2], f2u64(v2[0], v2[1]));
        else
          st_coh8(&ghws[((size_t)(nt_g - 64) * 64 + b) * 16 + clp * 2], f2u64(v2[0], v2[1]));
      }
    }
    ARRIVE_PRE();
    if (tid == 0) st_coh1(&af[bid * 32], genA);      // A done

    // ===== B1-wait: 4 q-producer blocks done =====
    if (tid < 64) {
      for (;;) {
        bool ok = true;
        if (lane < 4) ok = ld_coh1(&af[pqsel * 32]) >= genA;
        if (__all(ok)) break;
        __builtin_amdgcn_s_sleep(1);
      }
    }
    __syncthreads();

    // ===== Phase B1: e_partial over pinned pk slice =====
    {
      float* ep_s = (float*)scr;   // [128]
      float qr2[4];
      {
        const u64* qb = (const u64*)(qws + (size_t)batt * Hh + hq * 256);
        u64 q01 = ld_coh8(qb + lane * 2), q23 = ld_coh8(qb + lane * 2 + 1);
        qr2[0] = u64lo(q01); qr2[1] = u64hi(q01);
        qr2[2] = u64lo(q23); qr2[3] = u64hi(q23);
      }
      for (int si = 0; si < 16; ++si) {
        int s = wv * 16 + si;
        u64 pkv = *(const u64*)&pk_l[s][lane << 2];
        float pv0 = __uint_as_float(((unsigned)pkv & 0xffffu) << 16);
        float pv1 = __uint_as_float((unsigned)pkv & 0xffff0000u);
        float pv2 = __uint_as_float(((unsigned)(pkv >> 32) & 0xffffu) << 16);
        float pv3 = __uint_as_float((unsigned)(pkv >> 32) & 0xffff0000u);
        float p = vr2[0] * fast_tanh(qr2[0] + pv0);
        p = fmaf(vr2[1], fast_tanh(qr2[1] + pv1), p);
        p = fmaf(vr2[2], fast_tanh(qr2[2] + pv2), p);
        p = fmaf(vr2[3], fast_tanh(qr2[3] + pv3), p);
        #pragma unroll
        for (int m = 1; m < 64; m <<= 1) p += __shfl_xor(p, m, 64);
        if (lane == 0) ep_s[s] = p;
      }
      __syncthreads();
      if (tid < 64) {
        float2 e2 = *(const float2*)&ep_s[tid * 2];
        st_coh8(&epart[((size_t)batt * 4 + hq) * 128 + tid * 2], f2u64(e2.x, e2.y));
      }
    }
    ARRIVE_PRE();
    if (tid == 0) add_coh1(&mb[batt * 32], 1u);      // B1 arrival

    // prefetch B2's enc words into regs (alpha-independent) — overlaps mb-wait
    unsigned ur[32];
    {
      int tq = tid >> 7, hh = tid & 127;
      const unsigned short* ebase = encb + ((size_t)batt * Ss + tq * 32) * Hh
                                  + hq * 256 + hh * 2;
      #pragma unroll
      for (int s2 = 0; s2 < 32; ++s2)
        ur[s2] = *(const unsigned*)(ebase + (size_t)s2 * Hh);
    }

    // B2-wait: all 4 sibling epart slices
    if (tid == 0) {
      while (ld_coh1(&mb[batt * 32]) < 4u * genA) __builtin_amdgcn_s_sleep(1);
    }
    __syncthreads();

    // ===== Phase B2: softmax + ctx slice =====
    {
      float* e_s  = (float*)(scr + 512);
      float* al_s = (float*)(scr + 1024);
      float* comb = (float*)(scr + 1536);
      if (tid < 64) {
        float s0 = 0.f, s1 = 0.f;
        #pragma unroll
        for (int k = 0; k < 4; ++k) {
          u64 v = ld_coh8(&epart[((size_t)batt * 4 + k) * 128 + tid * 2]);
          s0 += u64lo(v); s1 += u64hi(v);
        }
        e_s[tid * 2] = s0; e_s[tid * 2 + 1] = s1;
      }
      __syncthreads();
      if (wv == 0) {
        float x0 = e_s[lane], x1 = e_s[lane + 64];
        float m = fmaxf(x0, x1);
        #pragma unroll
        for (int mm = 1; mm < 64; mm <<= 1) m = fmaxf(m, __shfl_xor(m, mm, 64));
        float ex0 = __expf(x0 - m), ex1 = __expf(x1 - m);
        float ssum = ex0 + ex1;
        #pragma unroll
        for (int mm = 1; mm < 64; mm <<= 1) ssum += __shfl_xor(ssum, mm, 64);
        float inv = __fdividef(1.0f, ssum);
        al_s[lane] = ex0 * inv; al_s[lane + 64] = ex1 * inv;
      }
      __syncthreads();
      {
        int tq = tid >> 7, hh = tid & 127;
        float c0 = 0.f, c1 = 0.f;
        #pragma unroll 8
        for (int s2 = 0; s2 < 32; ++s2) {
          float al = al_s[tq * 32 + s2];
          unsigned u = ur[s2];
          c0 = fmaf(al, __uint_as_float((u & 0xffffu) << 16), c0);
          c1 = fmaf(al, __uint_as_float(u & 0xffff0000u), c1);
        }
        comb[(tq * 128 + hh) * 2 + 0] = c0;
        comb[(tq * 128 + hh) * 2 + 1] = c1;
      }
      __syncthreads();
      // (rc anti-dep wait removed — implied by af-chain, see flag comments)
      if (tid < 128) {
        float c0 = comb[tid * 2] + comb[(128 + tid) * 2]
                 + comb[(256 + tid) * 2] + comb[(384 + tid) * 2];
        float c1 = comb[tid * 2 + 1] + comb[(128 + tid) * 2 + 1]
                 + comb[(256 + tid) * 2 + 1] + comb[(384 + tid) * 2 + 1];
        int h = hq * 256 + tid * 2;
        int kt = h >> 5, qd = (h >> 3) & 3, elem = h & 7;
        int lf = (batt & 15) | (qd << 4);
        unsigned hw = f2bf(c0) | (f2bf(c1) << 16);
        st_coh1(ctxf + ((size_t)((batt >> 4) * 32 + kt) * 64 + lf) * 8 + elem, hw);
      }
    }
    ARRIVE_PRE();
    if (tid == 0) add_coh1(&cc[batt * 32], 1u);      // ctx slice stored

    // ===== Phase C (r11 overlap structure): gate loads + x-half MFMA over cc-wait =====
    {
      const int jb = jbC;
      const int bq = bqC;
      const int g  = wv >> 1;
      const int kh = wv & 1;
      const int ntp = jb * 3 + g;
      // quick wait: gh producers of step t (2 flags; A finished long ago)
      if (tid < 64) {
        for (;;) {
          bool ok = true;
          if (lane < 2) ok = ld_coh1(&af[pghsel2 * 32]) >= genA;
          if (__all(ok)) break;
          __builtin_amdgcn_s_sleep(1);
        }
      }
      __syncthreads();
      // issue gate-input coherent loads EARLY (latency hides under x-MFMA + cc-wait)
      u64 g0 = 0, g1 = 0, g2 = 0, hpu = 0;
      if (tid < 128) {
        g0 = ld_coh8(&ghws[((size_t)(jb * 3 + 0) * 64 + bC) * 16 + jpC * 2]);
        g1 = ld_coh8(&ghws[((size_t)(jb * 3 + 1) * 64 + bC) * 16 + jpC * 2]);
        g2 = ld_coh8(&ghws[((size_t)(jb * 3 + 2) * 64 + bC) * 16 + jpC * 2]);
        hpu = ld_coh8(&hprv[(size_t)bC * Hh + j0pC]);
      }
      // x-half MFMA (kt<16) — needs only inputs, runs while cc-wait would block.
      f32x4 accC = {0.f, 0.f, 0.f, 0.f};
      if (wv < 6 && kh == 0) {
        for (int kt = 0; kt < 16; ++kt) {
          int brow = bq * 16 + col;
          short8 a = cvt8_reg(inputs + ((size_t)brow * Tt + t) * Ee + kt * 32 + quad * 8);
          short8 bfr = ld_frag(wihf, ntp * 48 + kt, lane);
          accC = __builtin_amdgcn_mfma_f32_16x16x32_bf16(a, bfr, accC, 0, 0, 0);
        }
      }
      // cc-wait: ctx tile bqC complete (16 batts x 4 arrivals)
      if (tid < 64) {
        for (;;) {
          bool ok = true;
          if (lane < 16) ok = ld_coh1(&cc[(bqC * 16 + lane) * 32]) >= 4u * genA;
          if (__all(ok)) break;
          __builtin_amdgcn_s_sleep(1);
        }
      }
      __syncthreads();
      // stage this btile's ctx frags (32 KB) into LDS coherently
      {
        u64* l8 = (u64*)scr;
        const u64* g8 = (const u64*)(ctxf + (size_t)bq * 32 * 64 * 8);
        u64 r[8];
        #pragma unroll
        for (int i = 0; i < 8; ++i) r[i] = ld_coh8(g8 + tid + i * NTHR);
        #pragma unroll
        for (int i = 0; i < 8; ++i) l8[tid + i * NTHR] = r[i];
      }
      __syncthreads();
      float* gxl = (float*)(scr + 32768);
      if (wv < 6) {
        const unsigned short* lctx = (const unsigned short*)scr;
        // remaining kts: kh==0 -> kt 16..23; kh==1 -> kt 24..47 (same order)
        int kt0 = kh ? 24 : 16;
        int kt1 = kh ? 48 : 24;
        for (int kt = kt0; kt < kt1; ++kt) {
          short8 a = *(const short8*)(lctx + ((size_t)(kt - 16) * 64 + lane) * 8);
          short8 bfr = ld_frag(wihf, ntp * 48 + kt, lane);
          accC = __builtin_amdgcn_mfma_f32_16x16x32_bf16(a, bfr, accC, 0, 0, 0);
        }
        #pragma unroll
        for (int r = 0; r < 4; ++r) gxl[r * 384 + wv * 64 + lane] = accC[r];
      }
      __syncthreads();
      // anti-dep: hfrg tile bqC readers (A blocks of step t) must have staged
      if (tid < 64) {
        unsigned tgt = 8u * genA;
        for (;;) {
          bool ok = true;
          if (lane < 8) ok = ld_coh1(&ha[(bqC * 8 + lane) * 32]) >= tgt;
          if (__all(ok)) break;
          __builtin_amdgcn_s_sleep(1);
        }
      }
      __syncthreads();
      if (tid < 128) {
        int qd = blocC >> 2, r = blocC & 3;
        float hn2[2];
        #pragma unroll
        for (int jj = 0; jj < 2; ++jj) {
          int cl = jpC * 2 + jj;
          int ll = (qd << 4) | cl;
          float gx0 = gxl[r * 384 + 0 * 64 + ll] + gxl[r * 384 + 1 * 64 + ll];
          float gx1 = gxl[r * 384 + 2 * 64 + ll] + gxl[r * 384 + 3 * 64 + ll];
          float gx2 = gxl[r * 384 + 4 * 64 + ll] + gxl[r * 384 + 5 * 64 + ll];
          float gh0 = jj ? u64hi(g0) : u64lo(g0);
          float gh1 = jj ? u64hi(g1) : u64lo(g1);
          float gh2 = jj ? u64hi(g2) : u64lo(g2);
          float hp  = jj ? u64hi(hpu) : u64lo(hpu);
          float bi0 = jj ? bi0v.y : bi0v.x;
          float bi1 = jj ? bi1v.y : bi1v.x;
          float bi2 = jj ? bi2v.y : bi2v.x;
          float bh0 = jj ? bh0v.y : bh0v.x;
          float bh1 = jj ? bh1v.y : bh1v.x;
          float bh2 = jj ? bh2v.y : bh2v.x;
          float rr = fast_sig(gx0 + bi0 + gh0 + bh0);
          float zz = fast_sig(gx1 + bi1 + gh1 + bh1);
          float nn = fast_tanh(gx2 + bi2 + rr * (gh2 + bh2));
          hn2[jj] = (1.0f - zz) * nn + zz * hp;
        }
        *(float2*)(outs + ((size_t)bC * Tt + t) * Hh + j0pC) = make_float2(hn2[0], hn2[1]);
        st_coh8(&hprv[(size_t)bC * Hh + j0pC], f2u64(hn2[0], hn2[1]));
        int kt = j0pC >> 5, qd2 = (j0pC >> 3) & 3;
        int lfh = (bC & 15) | (qd2 << 4);
        unsigned hw = f2bf(hn2[0]) | (f2bf(hn2[1]) << 16);
        st_coh1(hfrg + ((size_t)(bqC * 32 + kt) * 64 + lfh) * 8 + (j0pC & 7), hw);
      }
    }
    ARRIVE_PRE();
    if (tid == 0) add_coh1(&hc[(bqC * 8 + (jbC >> 3)) * 32], 1u);  // C done
  }

  grid.sync();
  // final hidden from hprv (coherent)
  {
    int idx = gtid;
    if (idx < Bb * Hh) {
      unsigned u = ld_coh1(&hprv[idx]);
      hidout[idx] = __uint_as_float(u);
    }
  }
}

extern "C" void kernel_launch(void* const* d_in, const int* in_sizes, int n_in,
                              void* d_out, int out_size, void* d_ws, size_t ws_size,
                              hipStream_t stream) {
  const float* inputs = (const float*)d_in[0];
  const float* enc    = (const float*)d_in[1];
  const float* finals = (const float*)d_in[2];
  const float* Wk  = (const float*)d_in[4];
  const float* Wq  = (const float*)d_in[5];
  const float* v   = (const float*)d_in[6];
  const float* Wih = (const float*)d_in[7];
  const float* Whh = (const float*)d_in[8];
  const float* bih = (const float*)d_in[9];
  const float* bhh = (const float*)d_in[10];
  float* out = (float*)d_out;
  char* ws   = (char*)d_ws;   // needs ~55.2 MB

  void* args[] = {(void*)&inputs, (void*)&enc, (void*)&finals, (void*)&Wk,
                  (void*)&Wq, (void*)&v, (void*)&Wih, (void*)&Whh,
                  (void*)&bih, (void*)&bhh, (void*)&out, (void*)&ws};
  (void)hipLaunchCooperativeKernel((const void*)bahdanau_kernel,
                                   dim3(GRID), dim3(NTHR), args, 0, stream);
}

// Round 14
// 3794.765 us; speedup vs baseline: 1.2828x; 1.2828x over previous
//
#include <hip/hip_runtime.h>
#include <hip/hip_cooperative_groups.h>

namespace cg = cooperative_groups;

#define Bb 64
#define Ss 128
#define Tt 128
#define Ee 512
#define Hh 1024
#define GRID 256
#define NTHR 512
#define GSTRIDE (GRID * NTHR)

using short8 = __attribute__((ext_vector_type(8))) short;
using f32x4  = __attribute__((ext_vector_type(4))) float;
typedef unsigned long long u64;

// ---- ws layout (byte offsets), total ~55.1 MiB ----
#define PK_OFF    0u            // ushort [8192][1024]  proj_key bf16 (dead after pin)
#define EPART_OFF PK_OFF        // float [64 b][4 hq][128 s]  (overlays pk, 128 KB)
#define ENC_OFF   16777216u     // ushort [64][128][1024] enc bf16
#define WQF_OFF   33554432u     // frag [64 nt][32 kt][64][8]   (contiguous with WHHF:
#define WHHF_OFF  35651584u     // frag [192 nt][32 kt][64][8]   unified nt = 0..255)
#define WIHF_OFF  41943040u     // frag [192 nt][48 kt][64][8] (perm rows)
#define WKF_OFF   51380224u     // frag [64 nt][32 kt][64][8]
#define QWS_OFF   53477376u     // float [64][1024]
#define GHWS_OFF  53739520u     // float [192 ntp][64 b][16 jj]
#define CTXF_OFF  54525952u     // frag A [4 btile][32 kt][64][8]  (128 KB)
#define HFRG_OFF  54657024u     // frag A [4 btile][32 kt][64][8]  (128 KB)
#define HPRV_OFF  54788096u     // float [64][1024]
#define FLG_OFF   55050240u     // uint region: dataflow flags/counters (64 KB)

__device__ __forceinline__ float fast_tanh(float x) {
  float e = __expf(2.0f * x);
  return 1.0f - __fdividef(2.0f, e + 1.0f);
}
__device__ __forceinline__ float fast_sig(float x) {
  return __fdividef(1.0f, 1.0f + __expf(-x));
}
__device__ __forceinline__ unsigned f2bf(float x) {
  union { float f; unsigned u; } v; v.f = x;
  unsigned r = v.u + 0x7fffu + ((v.u >> 16) & 1u);
  return (r >> 16);
}
__device__ __forceinline__ uint4 pack8(float4 a, float4 b) {
  uint4 u;
  u.x = f2bf(a.x) | (f2bf(a.y) << 16);
  u.y = f2bf(a.z) | (f2bf(a.w) << 16);
  u.z = f2bf(b.x) | (f2bf(b.y) << 16);
  u.w = f2bf(b.z) | (f2bf(b.w) << 16);
  return u;
}
__device__ __forceinline__ void cvt8_store(const float* src, unsigned short* dst) {
  float4 f0 = *(const float4*)src, f1 = *(const float4*)(src + 4);
  *(uint4*)dst = pack8(f0, f1);
}
__device__ __forceinline__ short8 ld_frag(const unsigned short* base, int tile, int lane) {
  return *(const short8*)(base + ((size_t)tile * 64 + lane) * 8);
}
__device__ __forceinline__ short8 cvt8_reg(const float* src) {
  float4 f0 = *(const float4*)src, f1 = *(const float4*)(src + 4);
  union { uint4 u; short8 s; } cv; cv.u = pack8(f0, f1);
  return cv.s;
}

// ---- coherent (device-scope, L2-safe) access helpers ----
__device__ __forceinline__ u64 ld_coh8(const void* p) {
  return __hip_atomic_load((const u64*)p, __ATOMIC_RELAXED, __HIP_MEMORY_SCOPE_AGENT);
}
__device__ __forceinline__ void st_coh8(void* p, u64 v) {
  __hip_atomic_store((u64*)p, v, __ATOMIC_RELAXED, __HIP_MEMORY_SCOPE_AGENT);
}
__device__ __forceinline__ unsigned ld_coh1(const void* p) {
  return __hip_atomic_load((const unsigned*)p, __ATOMIC_RELAXED, __HIP_MEMORY_SCOPE_AGENT);
}
__device__ __forceinline__ void st_coh1(void* p, unsigned v) {
  __hip_atomic_store((unsigned*)p, v, __ATOMIC_RELAXED, __HIP_MEMORY_SCOPE_AGENT);
}
__device__ __forceinline__ void add_coh1(void* p, unsigned v) {
  __hip_atomic_fetch_add((unsigned*)p, v, __ATOMIC_RELAXED, __HIP_MEMORY_SCOPE_AGENT);
}
__device__ __forceinline__ u64 f2u64(float a, float b) {
  union { float f[2]; u64 u; } c; c.f[0] = a; c.f[1] = b; return c.u;
}
__device__ __forceinline__ float u64lo(u64 v) {
  union { unsigned u; float f; } c; c.u = (unsigned)v; return c.f;
}
__device__ __forceinline__ float u64hi(u64 v) {
  union { unsigned u; float f; } c; c.u = (unsigned)(v >> 32); return c.f;
}

// producer arrive: drain stores block-wide, then tid0 sets/bumps the flag
#define ARRIVE_PRE() do { \
  asm volatile("s_waitcnt vmcnt(0)" ::: "memory"); \
  __syncthreads(); } while (0)

template <int K, bool PERM>
__device__ void conv_frag(const float* __restrict__ W, unsigned short* __restrict__ F,
                          int gtid, int total) {
  const int kpg = K / 8;
  for (int i = gtid; i < total; i += GSTRIDE) {
    int np = i / kpg, kg = i - np * kpg;
    int row;
    if (PERM) {
      int ntp = np >> 4, jb = ntp / 3, g = ntp - jb * 3;
      row = g * 1024 + jb * 16 + (np & 15);
    } else row = np;
    int k0 = kg * 8;
    int kt = k0 >> 5, quad = (k0 >> 3) & 3;
    int lane_f = (np & 15) | (quad << 4);
    size_t dst = ((size_t)((np >> 4) * (K / 32) + kt) * 64 + lane_f) * 8;
    cvt8_store(W + (size_t)row * K + k0, F + dst);
  }
}

__global__ void __launch_bounds__(NTHR, 2)
bahdanau_kernel(const float* __restrict__ inputs,
                const float* __restrict__ enc,
                const float* __restrict__ finals,
                const float* __restrict__ Wk,
                const float* __restrict__ Wq,
                const float* __restrict__ vatt,
                const float* __restrict__ Wih,
                const float* __restrict__ Whh,
                const float* __restrict__ bih,
                const float* __restrict__ bhh,
                float* __restrict__ dout,
                char* __restrict__ wsb)
{
  cg::grid_group grid = cg::this_grid();
  __shared__ unsigned short pk_l[128][256];
  __shared__ char scr[40960];

  const int tid  = threadIdx.x;
  const int bid  = blockIdx.x;
  const int lane = tid & 63;
  const int wv   = __builtin_amdgcn_readfirstlane(tid >> 6);   // 0..7
  const int gtid = bid * NTHR + tid;
  const int quad = lane >> 4, col = lane & 15;

  unsigned short* pk   = (unsigned short*)(wsb + PK_OFF);
  float*          epart= (float*)(wsb + EPART_OFF);
  unsigned short* encb = (unsigned short*)(wsb + ENC_OFF);
  unsigned short* wqf  = (unsigned short*)(wsb + WQF_OFF);  // unified nt 0..255 (wq|whh)
  unsigned short* wihf = (unsigned short*)(wsb + WIHF_OFF);
  unsigned short* wkf  = (unsigned short*)(wsb + WKF_OFF);
  float* qws  = (float*)(wsb + QWS_OFF);
  float* ghws = (float*)(wsb + GHWS_OFF);
  unsigned short* ctxf = (unsigned short*)(wsb + CTXF_OFF);
  unsigned short* hfrg = (unsigned short*)(wsb + HFRG_OFF);
  float* hprv = (float*)(wsb + HPRV_OFF);
  unsigned* flags = (unsigned*)(wsb + FLG_OFF);
  // dataflow state, all slots 128B-strided, monotone (never reset):
  unsigned* af = flags;              // [256 blk]  A done (q/gh stored), value t+1
  unsigned* mb = flags + 8192;       // [64 batt]  B1 arrivals (4/step)
  unsigned* cc = flags + 10240;      // [64 batt]  B2 ctx-stored arrivals (4/step)
  unsigned* hc = flags + 12288;      // [4 bt][8]  C done arrivals (8/step each)
  // rc REMOVED (r14, single-variable): B2(batt,t) transitively follows full
  // C(.,bq=batt>>4) completion at t-1 via B1's af-wait (A passed its hc-wait,
  // and C's ctx staging precedes its hc arrive). ha retained.
  unsigned* ha = flags + 14336;      // [4 bt][8]  A staged hfrg (reader release, 8/step)
  float* hidout = dout;
  float* outs   = dout + Bb * Hh;

  const int batt = bid & 63;          // attention batch
  const int hq   = bid >> 6;          // H quarter

  // ================= P0: conversions + flag init ====
  for (int i = gtid; i < 16384; i += GSTRIDE) flags[i] = 0u;
  for (int i = gtid; i < 1048576; i += GSTRIDE)
    cvt8_store(enc + (size_t)i * 8, encb + (size_t)i * 8);
  conv_frag<1024, false>(Wq,  wqf,  gtid, 131072);
  conv_frag<1024, false>(Wk,  wkf,  gtid, 131072);
  conv_frag<1024, true >(Whh, (unsigned short*)(wsb + WHHF_OFF), gtid, 393216);
  conv_frag<1536, true >(Wih, wihf, gtid, 589824);
  for (int i = gtid; i < 8192; i += GSTRIDE) {
    int b = i >> 7, kg = i & 127, k0 = kg * 8;
    int kt = k0 >> 5, qd = (k0 >> 3) & 3;
    int lf = (b & 15) | (qd << 4);
    cvt8_store(finals + (size_t)b * Hh + k0,
               hfrg + ((size_t)((b >> 4) * 32 + kt) * 64 + lf) * 8);
  }
  for (int i = gtid; i < 16384; i += GSTRIDE)
    ((float4*)hprv)[i] = ((const float4*)finals)[i];
  grid.sync();

  // ---- Phase-A tiling (r9): window wA (4 col-tiles) x batch-tile btA ----
  const int wA  = (bid & 7) * 8 + (bid >> 5);    // 0..63
  const int btA = (bid >> 3) & 3;                // 0..3
  const int cgA = wv & 3;
  const int khA = wv >> 2;
  const int ntA = wA * 4 + cgA;                  // unified col-tile 0..255
  short8 wAB[16];
  #pragma unroll
  for (int i = 0; i < 16; ++i)
    wAB[i] = ld_frag(wqf, ntA * 32 + khA * 16 + i, lane);

  // Phase-C role (r9 remap)
  const int cxC = bid & 7, cmC = bid >> 3;
  const int jbC = cxC * 8 + (cmC >> 2);   // 0..63
  const int bqC = cmC & 3;                // 0..3

  // ---- dataflow producer ids (precomputed) ----
  // B1 q-producers: windows hq*4+g, batch-tile batt>>4
  int pqsel;
  {
    int g = lane & 3;
    int wq = hq * 4 + g;
    pqsel = (wq & 7) * 32 + (batt >> 4) * 8 + (wq >> 3);
  }
  // C gh-producers: windows covering col-tiles 64+3*jbC .. 66+3*jbC, bt=bqC
  int pghsel2;
  {
    int wg0 = (64 + 3 * jbC) >> 2, wg1 = (66 + 3 * jbC) >> 2;
    int wgx = (lane & 1) ? wg1 : wg0;
    pghsel2 = (wgx & 7) * 32 + bqC * 8 + (wgx >> 3);
  }

  // vatt slice for B1 — hoisted
  float vr2[4];
  {
    float4 vv = *(const float4*)(vatt + hq * 256 + lane * 4);
    vr2[0] = vv.x; vr2[1] = vv.y; vr2[2] = vv.z; vr2[3] = vv.w;
  }

  // Phase-C loop-invariant gate biases (hoisted out of t-loop)
  const int blocC = tid >> 3, jpC = tid & 7;
  const int bC    = bqC * 16 + blocC;
  const int j0pC  = jbC * 16 + jpC * 2;
  float2 bi0v = {0,0}, bi1v = {0,0}, bi2v = {0,0};
  float2 bh0v = {0,0}, bh1v = {0,0}, bh2v = {0,0};
  if (tid < 128) {
    bi0v = *(const float2*)&bih[0 * 1024 + j0pC];
    bi1v = *(const float2*)&bih[1 * 1024 + j0pC];
    bi2v = *(const float2*)&bih[2 * 1024 + j0pC];
    bh0v = *(const float2*)&bhh[0 * 1024 + j0pC];
    bh1v = *(const float2*)&bhh[1 * 1024 + j0pC];
    bh2v = *(const float2*)&bhh[2 * 1024 + j0pC];
  }

  // ================= P0b: proj_key = enc @ Wk^T (MFMA) =================
  {
    const int W = bid * 8 + wv;
    const int mt = W >> 2;
    const int ng = W & 3;
    for (int nt2 = 0; nt2 < 16; ++nt2) {
      int nt = ng * 16 + nt2;
      f32x4 acc = {0.f, 0.f, 0.f, 0.f};
      for (int kt = 0; kt < 32; ++kt) {
        short8 a = *(const short8*)(encb + (size_t)(mt * 16 + col) * Hh + kt * 32 + quad * 8);
        short8 b = ld_frag(wkf, nt * 32 + kt, lane);
        acc = __builtin_amdgcn_mfma_f32_16x16x32_bf16(a, b, acc, 0, 0, 0);
      }
      #pragma unroll
      for (int r = 0; r < 4; ++r)
        pk[(size_t)(mt * 16 + quad * 4 + r) * Hh + nt * 16 + col] = (unsigned short)f2bf(acc[r]);
    }
  }
  grid.sync();

  // ---- pin pk slice [128 s][256 h] into LDS ----
  {
    const unsigned short* src = pk + (size_t)batt * Ss * Hh + hq * 256;
    int s = tid >> 2, pq = tid & 3;
    #pragma unroll
    for (int i = 0; i < 8; ++i)
      *(uint4*)&pk_l[s][pq * 64 + i * 8] =
        *(const uint4*)(src + (size_t)s * Hh + pq * 64 + i * 8);
  }
  __syncthreads();

  for (int t = 0; t < Tt; ++t) {
    const unsigned genA = (unsigned)(t + 1);

    // ===== A-wait: hfrg tile btA fully rewritten by C(t-1) =====
    __syncthreads();
    if (t > 0 && tid < 64) {
      unsigned tgt = 8u * (unsigned)t;
      for (;;) {
        bool ok = true;
        if (lane < 8) ok = ld_coh1(&hc[(btA * 8 + lane) * 32]) >= tgt;
        if (__all(ok)) break;
        __builtin_amdgcn_s_sleep(2);
      }
    }
    __syncthreads();

    // ===== Phase A: [q ; gh] tile (16 b x 64 cols), h-slice staged in LDS =====
    {
      {
        u64* l8 = (u64*)scr;
        const u64* g8 = (const u64*)(hfrg + (size_t)btA * 32 * 64 * 8);
        u64 r[8];
        #pragma unroll
        for (int i = 0; i < 8; ++i) r[i] = ld_coh8(g8 + tid + i * NTHR);
        #pragma unroll
        for (int i = 0; i < 8; ++i) l8[tid + i * NTHR] = r[i];
      }
      __syncthreads();
      if (tid == 0) add_coh1(&ha[(btA * 8 + (wA >> 3)) * 32], 1u);  // release hfrg readers
      const unsigned short* hl = (const unsigned short*)scr;
      f32x4 acc = {0.f, 0.f, 0.f, 0.f};
      #pragma unroll
      for (int i = 0; i < 16; ++i) {
        int kt = khA * 16 + i;
        short8 a = *(const short8*)(hl + ((size_t)kt * 64 + lane) * 8);
        acc = __builtin_amdgcn_mfma_f32_16x16x32_bf16(a, wAB[i], acc, 0, 0, 0);
      }
      __syncthreads();
      float* part = (float*)(scr + 32768);   // [4 r][8 wv][64 lane]
      #pragma unroll
      for (int r = 0; r < 4; ++r) part[r * 512 + wv * 64 + lane] = acc[r];
      __syncthreads();
      {
        int cg = tid >> 7, rem = tid & 127;
        int qd = rem >> 5, r = (rem >> 3) & 3, clp = rem & 7;
        float v2[2];
        #pragma unroll
        for (int jj = 0; jj < 2; ++jj) {
          int cl = clp * 2 + jj;
          int ln = (qd << 4) | cl;
          v2[jj] = part[r * 512 + cg * 64 + ln]
                 + part[r * 512 + (4 + cg) * 64 + ln];
        }
        int b = btA * 16 + qd * 4 + r;
        int nt_g = wA * 4 + cg;
        if (nt_g < 64)
          st_coh8(&qws[(size_t)b * Hh + nt_g * 16 + clp * 2], f2u64(v2[0], v2[1]));
        else
          st_coh8(&ghws[((size_t)(nt_g - 64) * 64 + b) * 16 + clp * 2], f2u64(v2[0], v2[1]));
      }
    }
    ARRIVE_PRE();
    if (tid == 0) st_coh1(&af[bid * 32], genA);      // A done

    // ===== B1-wait: 4 q-producer blocks done =====
    if (tid < 64) {
      for (;;) {
        bool ok = true;
        if (lane < 4) ok = ld_coh1(&af[pqsel * 32]) >= genA;
        if (__all(ok)) break;
        __builtin_amdgcn_s_sleep(2);
      }
    }
    __syncthreads();

    // ===== Phase B1: e_partial over pinned pk slice =====
    {
      float* ep_s = (float*)scr;   // [128]
      float qr2[4];
      {
        const u64* qb = (const u64*)(qws + (size_t)batt * Hh + hq * 256);
        u64 q01 = ld_coh8(qb + lane * 2), q23 = ld_coh8(qb + lane * 2 + 1);
        qr2[0] = u64lo(q01); qr2[1] = u64hi(q01);
        qr2[2] = u64lo(q23); qr2[3] = u64hi(q23);
      }
      for (int si = 0; si < 16; ++si) {
        int s = wv * 16 + si;
        u64 pkv = *(const u64*)&pk_l[s][lane << 2];
        float pv0 = __uint_as_float(((unsigned)pkv & 0xffffu) << 16);
        float pv1 = __uint_as_float((unsigned)pkv & 0xffff0000u);
        float pv2 = __uint_as_float(((unsigned)(pkv >> 32) & 0xffffu) << 16);
        float pv3 = __uint_as_float((unsigned)(pkv >> 32) & 0xffff0000u);
        float p = vr2[0] * fast_tanh(qr2[0] + pv0);
        p = fmaf(vr2[1], fast_tanh(qr2[1] + pv1), p);
        p = fmaf(vr2[2], fast_tanh(qr2[2] + pv2), p);
        p = fmaf(vr2[3], fast_tanh(qr2[3] + pv3), p);
        #pragma unroll
        for (int m = 1; m < 64; m <<= 1) p += __shfl_xor(p, m, 64);
        if (lane == 0) ep_s[s] = p;
      }
      __syncthreads();
      if (tid < 64) {
        float2 e2 = *(const float2*)&ep_s[tid * 2];
        st_coh8(&epart[((size_t)batt * 4 + hq) * 128 + tid * 2], f2u64(e2.x, e2.y));
      }
    }
    ARRIVE_PRE();
    if (tid == 0) add_coh1(&mb[batt * 32], 1u);      // B1 arrival
    // B2-wait: all 4 sibling epart slices
    if (tid == 0) {
      while (ld_coh1(&mb[batt * 32]) < 4u * genA) __builtin_amdgcn_s_sleep(2);
    }
    __syncthreads();

    // ===== Phase B2: softmax + ctx slice =====
    {
      float* e_s  = (float*)(scr + 512);
      float* al_s = (float*)(scr + 1024);
      float* comb = (float*)(scr + 1536);
      if (tid < 64) {
        float s0 = 0.f, s1 = 0.f;
        #pragma unroll
        for (int k = 0; k < 4; ++k) {
          u64 v = ld_coh8(&epart[((size_t)batt * 4 + k) * 128 + tid * 2]);
          s0 += u64lo(v); s1 += u64hi(v);
        }
        e_s[tid * 2] = s0; e_s[tid * 2 + 1] = s1;
      }
      __syncthreads();
      if (wv == 0) {
        float x0 = e_s[lane], x1 = e_s[lane + 64];
        float m = fmaxf(x0, x1);
        #pragma unroll
        for (int mm = 1; mm < 64; mm <<= 1) m = fmaxf(m, __shfl_xor(m, mm, 64));
        float ex0 = __expf(x0 - m), ex1 = __expf(x1 - m);
        float ssum = ex0 + ex1;
        #pragma unroll
        for (int mm = 1; mm < 64; mm <<= 1) ssum += __shfl_xor(ssum, mm, 64);
        float inv = __fdividef(1.0f, ssum);
        al_s[lane] = ex0 * inv; al_s[lane + 64] = ex1 * inv;
      }
      __syncthreads();
      {
        int tq = tid >> 7, hh = tid & 127;
        float c0 = 0.f, c1 = 0.f;
        const unsigned short* ebase = encb + ((size_t)batt * Ss + tq * 32) * Hh
                                    + hq * 256 + hh * 2;
        #pragma unroll 8
        for (int s2 = 0; s2 < 32; ++s2) {
          float al = al_s[tq * 32 + s2];
          unsigned u = *(const unsigned*)(ebase + (size_t)s2 * Hh);
          c0 = fmaf(al, __uint_as_float((u & 0xffffu) << 16), c0);
          c1 = fmaf(al, __uint_as_float(u & 0xffff0000u), c1);
        }
        comb[(tq * 128 + hh) * 2 + 0] = c0;
        comb[(tq * 128 + hh) * 2 + 1] = c1;
      }
      __syncthreads();
      // (rc anti-dep wait removed — implied transitively by af-chain)
      if (tid < 128) {
        float c0 = comb[tid * 2] + comb[(128 + tid) * 2]
                 + comb[(256 + tid) * 2] + comb[(384 + tid) * 2];
        float c1 = comb[tid * 2 + 1] + comb[(128 + tid) * 2 + 1]
                 + comb[(256 + tid) * 2 + 1] + comb[(384 + tid) * 2 + 1];
        int h = hq * 256 + tid * 2;
        int kt = h >> 5, qd = (h >> 3) & 3, elem = h & 7;
        int lf = (batt & 15) | (qd << 4);
        unsigned hw = f2bf(c0) | (f2bf(c1) << 16);
        st_coh1(ctxf + ((size_t)((batt >> 4) * 32 + kt) * 64 + lf) * 8 + elem, hw);
      }
    }
    ARRIVE_PRE();
    if (tid == 0) add_coh1(&cc[batt * 32], 1u);      // ctx slice stored

    // ===== Phase C (r11 overlap structure): gate loads + x-half MFMA over cc-wait =====
    {
      const int jb = jbC;
      const int bq = bqC;
      const int g  = wv >> 1;
      const int kh = wv & 1;
      const int ntp = jb * 3 + g;
      // quick wait: gh producers of step t (2 flags; A finished long ago)
      if (tid < 64) {
        for (;;) {
          bool ok = true;
          if (lane < 2) ok = ld_coh1(&af[pghsel2 * 32]) >= genA;
          if (__all(ok)) break;
          __builtin_amdgcn_s_sleep(2);
        }
      }
      __syncthreads();
      // issue gate-input coherent loads EARLY (latency hides under x-MFMA + cc-wait)
      u64 g0 = 0, g1 = 0, g2 = 0, hpu = 0;
      if (tid < 128) {
        g0 = ld_coh8(&ghws[((size_t)(jb * 3 + 0) * 64 + bC) * 16 + jpC * 2]);
        g1 = ld_coh8(&ghws[((size_t)(jb * 3 + 1) * 64 + bC) * 16 + jpC * 2]);
        g2 = ld_coh8(&ghws[((size_t)(jb * 3 + 2) * 64 + bC) * 16 + jpC * 2]);
        hpu = ld_coh8(&hprv[(size_t)bC * Hh + j0pC]);
      }
      // x-half MFMA (kt<16) — needs only inputs, runs while cc-wait would block.
      f32x4 accC = {0.f, 0.f, 0.f, 0.f};
      if (wv < 6 && kh == 0) {
        for (int kt = 0; kt < 16; ++kt) {
          int brow = bq * 16 + col;
          short8 a = cvt8_reg(inputs + ((size_t)brow * Tt + t) * Ee + kt * 32 + quad * 8);
          short8 bfr = ld_frag(wihf, ntp * 48 + kt, lane);
          accC = __builtin_amdgcn_mfma_f32_16x16x32_bf16(a, bfr, accC, 0, 0, 0);
        }
      }
      // cc-wait: ctx tile bqC complete (16 batts x 4 arrivals)
      if (tid < 64) {
        for (;;) {
          bool ok = true;
          if (lane < 16) ok = ld_coh1(&cc[(bqC * 16 + lane) * 32]) >= 4u * genA;
          if (__all(ok)) break;
          __builtin_amdgcn_s_sleep(2);
        }
      }
      __syncthreads();
      // stage this btile's ctx frags (32 KB) into LDS coherently
      {
        u64* l8 = (u64*)scr;
        const u64* g8 = (const u64*)(ctxf + (size_t)bq * 32 * 64 * 8);
        u64 r[8];
        #pragma unroll
        for (int i = 0; i < 8; ++i) r[i] = ld_coh8(g8 + tid + i * NTHR);
        #pragma unroll
        for (int i = 0; i < 8; ++i) l8[tid + i * NTHR] = r[i];
      }
      __syncthreads();
      float* gxl = (float*)(scr + 32768);
      if (wv < 6) {
        const unsigned short* lctx = (const unsigned short*)scr;
        // remaining kts: kh==0 -> kt 16..23; kh==1 -> kt 24..47 (same order)
        int kt0 = kh ? 24 : 16;
        int kt1 = kh ? 48 : 24;
        for (int kt = kt0; kt < kt1; ++kt) {
          short8 a = *(const short8*)(lctx + ((size_t)(kt - 16) * 64 + lane) * 8);
          short8 bfr = ld_frag(wihf, ntp * 48 + kt, lane);
          accC = __builtin_amdgcn_mfma_f32_16x16x32_bf16(a, bfr, accC, 0, 0, 0);
        }
        #pragma unroll
        for (int r = 0; r < 4; ++r) gxl[r * 384 + wv * 64 + lane] = accC[r];
      }
      __syncthreads();
      // anti-dep: hfrg tile bqC readers (A blocks of step t) must have staged
      if (tid < 64) {
        unsigned tgt = 8u * genA;
        for (;;) {
          bool ok = true;
          if (lane < 8) ok = ld_coh1(&ha[(bqC * 8 + lane) * 32]) >= tgt;
          if (__all(ok)) break;
          __builtin_amdgcn_s_sleep(2);
        }
      }
      __syncthreads();
      if (tid < 128) {
        int qd = blocC >> 2, r = blocC & 3;
        float hn2[2];
        #pragma unroll
        for (int jj = 0; jj < 2; ++jj) {
          int cl = jpC * 2 + jj;
          int ll = (qd << 4) | cl;
          float gx0 = gxl[r * 384 + 0 * 64 + ll] + gxl[r * 384 + 1 * 64 + ll];
          float gx1 = gxl[r * 384 + 2 * 64 + ll] + gxl[r * 384 + 3 * 64 + ll];
          float gx2 = gxl[r * 384 + 4 * 64 + ll] + gxl[r * 384 + 5 * 64 + ll];
          float gh0 = jj ? u64hi(g0) : u64lo(g0);
          float gh1 = jj ? u64hi(g1) : u64lo(g1);
          float gh2 = jj ? u64hi(g2) : u64lo(g2);
          float hp  = jj ? u64hi(hpu) : u64lo(hpu);
          float bi0 = jj ? bi0v.y : bi0v.x;
          float bi1 = jj ? bi1v.y : bi1v.x;
          float bi2 = jj ? bi2v.y : bi2v.x;
          float bh0 = jj ? bh0v.y : bh0v.x;
          float bh1 = jj ? bh1v.y : bh1v.x;
          float bh2 = jj ? bh2v.y : bh2v.x;
          float rr = fast_sig(gx0 + bi0 + gh0 + bh0);
          float zz = fast_sig(gx1 + bi1 + gh1 + bh1);
          float nn = fast_tanh(gx2 + bi2 + rr * (gh2 + bh2));
          hn2[jj] = (1.0f - zz) * nn + zz * hp;
        }
        *(float2*)(outs + ((size_t)bC * Tt + t) * Hh + j0pC) = make_float2(hn2[0], hn2[1]);
        st_coh8(&hprv[(size_t)bC * Hh + j0pC], f2u64(hn2[0], hn2[1]));
        int kt = j0pC >> 5, qd2 = (j0pC >> 3) & 3;
        int lfh = (bC & 15) | (qd2 << 4);
        unsigned hw = f2bf(hn2[0]) | (f2bf(hn2[1]) << 16);
        st_coh1(hfrg + ((size_t)(bqC * 32 + kt) * 64 + lfh) * 8 + (j0pC & 7), hw);
      }
    }
    ARRIVE_PRE();
    if (tid == 0) add_coh1(&hc[(bqC * 8 + (jbC >> 3)) * 32], 1u);  // C done
  }

  grid.sync();
  // final hidden from hprv (coherent)
  {
    int idx = gtid;
    if (idx < Bb * Hh) {
      unsigned u = ld_coh1(&hprv[idx]);
      hidout[idx] = __uint_as_float(u);
    }
  }
}

extern "C" void kernel_launch(void* const* d_in, const int* in_sizes, int n_in,
                              void* d_out, int out_size, void* d_ws, size_t ws_size,
                              hipStream_t stream) {
  const float* inputs = (const float*)d_in[0];
  const float* enc    = (const float*)d_in[1];
  const float* finals = (const float*)d_in[2];
  const float* Wk  = (const float*)d_in[4];
  const float* Wq  = (const float*)d_in[5];
  const float* v   = (const float*)d_in[6];
  const float* Wih = (const float*)d_in[7];
  const float* Whh = (const float*)d_in[8];
  const float* bih = (const float*)d_in[9];
  const float* bhh = (const float*)d_in[10];
  float* out = (float*)d_out;
  char* ws   = (char*)d_ws;   // needs ~55.2 MB

  void* args[] = {(void*)&inputs, (void*)&enc, (void*)&finals, (void*)&Wk,
                  (void*)&Wq, (void*)&v, (void*)&Wih, (void*)&Whh,
                  (void*)&bih, (void*)&bhh, (void*)&out, (void*)&ws};
  (void)hipLaunchCooperativeKernel((const void*)bahdanau_kernel,
                                   dim3(GRID), dim3(NTHR), args, 0, stream);
}